// Round 1
// baseline (1096.682 us; speedup 1.0000x reference)
//
#include <hip/hip_runtime.h>

#define NN 512
#define BATCH 256

// ---------------------------------------------------------------------------
// Kernel 1: per-row max (value, min col achieving it) for all B*N rows.
// One 64-lane wave per row; 4 waves (256 threads) per block.
// ---------------------------------------------------------------------------
__global__ __launch_bounds__(256) void rowmax_init(const float* __restrict__ s,
                                                   float* __restrict__ rmax_val,
                                                   int* __restrict__ rmax_col) {
    const int wave = threadIdx.x >> 6;
    const int lane = threadIdx.x & 63;
    const long long row_g = (long long)blockIdx.x * 4 + wave; // 0 .. B*N-1

    const float* rp = s + row_g * NN;
    const float4 a = *(const float4*)(rp + 4 * lane);
    const float4 b = *(const float4*)(rp + 256 + 4 * lane);

    // ascending-col scan with strict '>' keeps the minimum col on ties
    float bv = a.x; int bc = 4 * lane;
    if (a.y > bv) { bv = a.y; bc = 4 * lane + 1; }
    if (a.z > bv) { bv = a.z; bc = 4 * lane + 2; }
    if (a.w > bv) { bv = a.w; bc = 4 * lane + 3; }
    if (b.x > bv) { bv = b.x; bc = 256 + 4 * lane; }
    if (b.y > bv) { bv = b.y; bc = 256 + 4 * lane + 1; }
    if (b.z > bv) { bv = b.z; bc = 256 + 4 * lane + 2; }
    if (b.w > bv) { bv = b.w; bc = 256 + 4 * lane + 3; }

    #pragma unroll
    for (int off = 32; off; off >>= 1) {
        float ov = __shfl_xor(bv, off);
        int   oc = __shfl_xor(bc, off);
        if (ov > bv || (ov == bv && oc < bc)) { bv = ov; bc = oc; }
    }
    if (lane == 0) {
        rmax_val[row_g] = bv;
        rmax_col[row_g] = bc;
    }
}

// ---------------------------------------------------------------------------
// Kernel 2: sequential greedy matching, one wave per batch element.
// Lane t owns rows {t + 64k : k=0..7} (rowmax cached in registers) and
// cols {4t..4t+3} U {256+4t..256+4t+3} (active flags in an 8-bit mask).
// Each step: wave argmax over cached row maxima (exact flat-argmax
// tie-breaking), write the selected output row, kill row+col, re-scan
// only rows whose cached argmax col was just killed.
// ---------------------------------------------------------------------------
__global__ __launch_bounds__(64) void greedy_match(const float* __restrict__ s,
                                                   const float* __restrict__ rmax_val,
                                                   const int* __restrict__ rmax_col,
                                                   float* __restrict__ out) {
    const int b = blockIdx.x;
    const int lane = threadIdx.x;
    const float* sb = s + (size_t)b * NN * NN;
    float* ob = out + (size_t)b * NN * NN;

    float rv[8];
    int   rc[8];
    #pragma unroll
    for (int k = 0; k < 8; ++k) {
        rv[k] = rmax_val[b * NN + lane + 64 * k];
        rc[k] = rmax_col[b * NN + lane + 64 * k];
    }
    unsigned colmask = 0xFFu;

    for (int step = 0; step < NN; ++step) {
        // ---- local best over this lane's 8 rows (rows ascending in k) ----
        float bv = rv[0]; int brow = lane; int bcol = rc[0];
        #pragma unroll
        for (int k = 1; k < 8; ++k) {
            if (rv[k] > bv) { bv = rv[k]; brow = lane + 64 * k; bcol = rc[k]; }
        }
        // ---- wave argmax: max val, then min row ----
        #pragma unroll
        for (int off = 32; off; off >>= 1) {
            float ov  = __shfl_xor(bv, off);
            int  orow = __shfl_xor(brow, off);
            int  ocol = __shfl_xor(bcol, off);
            if (ov > bv || (ov == bv && orow < brow)) { bv = ov; brow = orow; bcol = ocol; }
        }
        const int rstar = brow;
        const int cstar = bcol;

        // ---- write output row rstar (each row selected exactly once) ----
        float4 o0, o1;
        o0.x = (4 * lane + 0 == cstar) ? 1.0f : 0.0f;
        o0.y = (4 * lane + 1 == cstar) ? 1.0f : 0.0f;
        o0.z = (4 * lane + 2 == cstar) ? 1.0f : 0.0f;
        o0.w = (4 * lane + 3 == cstar) ? 1.0f : 0.0f;
        o1.x = (256 + 4 * lane + 0 == cstar) ? 1.0f : 0.0f;
        o1.y = (256 + 4 * lane + 1 == cstar) ? 1.0f : 0.0f;
        o1.z = (256 + 4 * lane + 2 == cstar) ? 1.0f : 0.0f;
        o1.w = (256 + 4 * lane + 3 == cstar) ? 1.0f : 0.0f;
        *(float4*)(ob + (size_t)rstar * NN + 4 * lane) = o0;
        *(float4*)(ob + (size_t)rstar * NN + 256 + 4 * lane) = o1;

        // ---- deactivate row rstar ----
        if ((rstar & 63) == lane) {
            #pragma unroll
            for (int k = 0; k < 8; ++k)
                if ((rstar >> 6) == k) rv[k] = -1.0f;
        }
        // ---- deactivate col cstar ----
        {
            const int hi    = cstar >> 8;           // 0 or 1
            const int owner = (cstar & 255) >> 2;   // owning lane
            const int bit   = (hi << 2) | (cstar & 3);
            if (lane == owner) colmask &= ~(1u << bit);
        }

        // ---- re-scan rows whose cached argmax col just died ----
        #pragma unroll
        for (int k = 0; k < 8; ++k) {
            const bool need = (rv[k] >= 0.0f) && (rc[k] == cstar);
            unsigned long long m = __ballot(need);
            while (m) {
                const int lr = __builtin_ctzll(m);
                m &= m - 1;
                const int row = lr + 64 * k;
                const float* rp = sb + (size_t)row * NN;
                const float4 a = *(const float4*)(rp + 4 * lane);
                const float4 c2 = *(const float4*)(rp + 256 + 4 * lane);
                float nv = -1.0f; int nc = 0;
                const float vals[8] = {a.x, a.y, a.z, a.w, c2.x, c2.y, c2.z, c2.w};
                #pragma unroll
                for (int i = 0; i < 8; ++i) {
                    const int col = (i < 4) ? (4 * lane + i) : (256 + 4 * lane + (i - 4));
                    if ((colmask >> i) & 1u) {
                        if (vals[i] > nv) { nv = vals[i]; nc = col; }
                    }
                }
                #pragma unroll
                for (int off = 32; off; off >>= 1) {
                    float ov = __shfl_xor(nv, off);
                    int  ocl = __shfl_xor(nc, off);
                    if (ov > nv || (ov == nv && ocl < nc)) { nv = ov; nc = ocl; }
                }
                if (lane == lr) { rv[k] = nv; rc[k] = nc; }
            }
        }
    }
}

extern "C" void kernel_launch(void* const* d_in, const int* in_sizes, int n_in,
                              void* d_out, int out_size, void* d_ws, size_t ws_size,
                              hipStream_t stream) {
    const float* s = (const float*)d_in[0];
    float* out = (float*)d_out;

    // workspace layout: rowmax values then rowmax cols (1 MB total)
    float* rmax_val = (float*)d_ws;
    int*   rmax_col = (int*)((char*)d_ws + (size_t)BATCH * NN * sizeof(float));

    rowmax_init<<<dim3(BATCH * NN / 4), dim3(256), 0, stream>>>(s, rmax_val, rmax_col);
    greedy_match<<<dim3(BATCH), dim3(64), 0, stream>>>(s, rmax_val, rmax_col, out);
}

// Round 2
// 784.393 us; speedup vs baseline: 1.3981x; 1.3981x over previous
//
#include <hip/hip_runtime.h>

#define NN 512
#define BATCH 256
#define T 8

// ---- DPP wave-64 max reduce: result lands in lane 63 (VALU-only, no LDS) ----
#define DPP_STEP(ctrl) x = fmaxf(x, __int_as_float(__builtin_amdgcn_update_dpp( \
        __float_as_int(x), __float_as_int(x), ctrl, 0xf, 0xf, false)));

__device__ __forceinline__ float wave_max_to63(float x) {
    DPP_STEP(0x111)  // row_shr:1
    DPP_STEP(0x112)  // row_shr:2
    DPP_STEP(0x114)  // row_shr:4
    DPP_STEP(0x118)  // row_shr:8
    DPP_STEP(0x142)  // row_bcast:15
    DPP_STEP(0x143)  // row_bcast:31
    return x;
}
__device__ __forceinline__ float bcast63(float x) {
    return __int_as_float(__builtin_amdgcn_readlane(__float_as_int(x), 63));
}
__device__ __forceinline__ unsigned long long pack_entry(float v, int c) {
    return ((unsigned long long)(unsigned)__float_as_int(v) << 32) | (unsigned)c;
}

// ---------------------------------------------------------------------------
// Kernel 1: per-row top-T (desc value, asc col on ties) written into the
// first NN*T u64 of each batch's out region (copied to LDS by kernel 2
// before any output row is stored there).
// ---------------------------------------------------------------------------
__global__ __launch_bounds__(256) void build_top(const float* __restrict__ s,
                                                 float* __restrict__ out) {
    const int wave = threadIdx.x >> 6;
    const int lane = threadIdx.x & 63;
    const int row_g = blockIdx.x * 4 + wave;       // 0 .. B*NN-1
    const int b = row_g >> 9;
    const int r = row_g & (NN - 1);
    const float* rp = s + (size_t)row_g * NN;
    unsigned long long* dst =
        (unsigned long long*)(out + (size_t)b * NN * NN) + (size_t)r * T;

    const float4 a  = *(const float4*)(rp + 4 * lane);
    const float4 c2 = *(const float4*)(rp + 256 + 4 * lane);
    float v[8] = {a.x, a.y, a.z, a.w, c2.x, c2.y, c2.z, c2.w};

    for (int t = 0; t < T; ++t) {
        // local best (ascending col order, strict > keeps min col)
        float bv = v[0]; int bslot = 0;
        #pragma unroll
        for (int i = 1; i < 8; ++i)
            if (v[i] > bv) { bv = v[i]; bslot = i; }
        const int bcol = (bslot < 4) ? (4 * lane + bslot) : (256 + 4 * lane + bslot - 4);

        const float smax = bcast63(wave_max_to63(bv));
        unsigned long long cm = __ballot(bv == smax);
        int bestc = 0x7FFFFFFF, bestl = 0;
        while (cm) {
            const int l = __builtin_ctzll(cm); cm &= cm - 1;
            const int cc = __builtin_amdgcn_readlane(bcol, l);
            if (cc < bestc) { bestc = cc; bestl = l; }
        }
        if (lane == bestl) {
            #pragma unroll
            for (int i = 0; i < 8; ++i)
                if (i == bslot) v[i] = -1.0f;
        }
        if (lane == 0) dst[t] = pack_entry(smax, bestc);
    }
}

// ---------------------------------------------------------------------------
// Kernel 2: sequential greedy matching, one wave per batch element.
// Per-row top-T candidate lists live in LDS; column-alive bytes in LDS;
// row state (current val/col/list ptr) in registers, 8 rows per lane.
// ---------------------------------------------------------------------------
__global__ __launch_bounds__(64) void greedy_match(const float* __restrict__ s,
                                                   float* __restrict__ out) {
    __shared__ unsigned long long lst[NN][T];   // 32 KB
    __shared__ unsigned char alive[NN];         // 512 B

    const int b = blockIdx.x;
    const int lane = threadIdx.x;
    const float* sb = s + (size_t)b * NN * NN;
    float* ob = out + (size_t)b * NN * NN;

    // ---- stage candidate lists from out-region into LDS ----
    {
        const ulonglong2* src = (const ulonglong2*)ob;
        ulonglong2* dstl = (ulonglong2*)&lst[0][0];
        #pragma unroll
        for (int j = 0; j < (NN * T / 2) / 64; ++j)      // 32 iters
            dstl[lane + 64 * j] = src[lane + 64 * j];
    }
    ((unsigned long long*)alive)[lane] = 0x0101010101010101ull;

    float rv[8]; int rc[8]; int ptr[8];
    unsigned colmask = 0xFFu;
    #pragma unroll
    for (int k = 0; k < 8; ++k) {
        const unsigned long long e = lst[lane + 64 * k][0];
        rv[k] = __int_as_float((int)(e >> 32));
        rc[k] = (int)(e & 0xFFFFFFFFull);
        ptr[k] = 0;
    }

    for (int step = 0; step < NN; ++step) {
        // ---- local best over this lane's 8 rows ----
        float bv = rv[0]; int brow = lane; int bcol = rc[0];
        #pragma unroll
        for (int k = 1; k < 8; ++k)
            if (rv[k] > bv) { bv = rv[k]; brow = lane + 64 * k; bcol = rc[k]; }

        // ---- wave argmax: DPP max + ballot + exact min-row tie-break ----
        const float smax = bcast63(wave_max_to63(bv));
        unsigned long long m = __ballot(bv == smax);
        int rstar = 0x7FFFFFFF, cstar = 0;
        while (m) {
            const int l = __builtin_ctzll(m); m &= m - 1;
            const int r = __builtin_amdgcn_readlane(brow, l);
            if (r < rstar) { rstar = r; cstar = __builtin_amdgcn_readlane(bcol, l); }
        }

        // ---- write output row rstar (each row selected exactly once) ----
        float4 o0, o1;
        o0.x = (4 * lane + 0 == cstar) ? 1.0f : 0.0f;
        o0.y = (4 * lane + 1 == cstar) ? 1.0f : 0.0f;
        o0.z = (4 * lane + 2 == cstar) ? 1.0f : 0.0f;
        o0.w = (4 * lane + 3 == cstar) ? 1.0f : 0.0f;
        o1.x = (256 + 4 * lane + 0 == cstar) ? 1.0f : 0.0f;
        o1.y = (256 + 4 * lane + 1 == cstar) ? 1.0f : 0.0f;
        o1.z = (256 + 4 * lane + 2 == cstar) ? 1.0f : 0.0f;
        o1.w = (256 + 4 * lane + 3 == cstar) ? 1.0f : 0.0f;
        *(float4*)(ob + (size_t)rstar * NN + 4 * lane) = o0;
        *(float4*)(ob + (size_t)rstar * NN + 256 + 4 * lane) = o1;

        // ---- kill row rstar ----
        if ((rstar & 63) == lane) {
            #pragma unroll
            for (int k = 0; k < 8; ++k)
                if ((rstar >> 6) == k) rv[k] = -1.0f;
        }
        // ---- kill col cstar (LDS byte + per-lane colmask for fallback) ----
        if (lane == 0) alive[cstar] = 0;
        {
            const int hi = cstar >> 8, owner = (cstar & 255) >> 2;
            const int bit = (hi << 2) | (cstar & 3);
            if (lane == owner) colmask &= ~(1u << bit);
        }

        // ---- rescan via LDS list walk (lanes proceed concurrently) ----
        unsigned fb = 0;
        #pragma unroll
        for (int k = 0; k < 8; ++k) {
            if (rv[k] >= 0.0f && rc[k] == cstar) {
                int p = ptr[k] + 1;
                for (;;) {
                    if (p >= T) { fb |= 1u << k; break; }
                    const unsigned long long e = lst[lane + 64 * k][p];
                    const float ev = __int_as_float((int)(e >> 32));
                    if (ev < 0.0f) { fb |= 1u << k; p = T; break; }  // sentinel
                    const int c = (int)(e & 0xFFFFFFFFull);
                    if (alive[c]) { rv[k] = ev; rc[k] = c; break; }
                    ++p;
                }
                ptr[k] = p;
            }
        }

        // ---- rare fallback: reload row from HBM, rebuild top-4 into LDS ----
        const unsigned long long anyfb = __ballot(fb != 0);
        if (anyfb) {
            #pragma unroll
            for (int k = 0; k < 8; ++k) {
                unsigned long long mk = __ballot((fb >> k) & 1u);
                while (mk) {
                    const int lr = __builtin_ctzll(mk); mk &= mk - 1;
                    const int row = lr + 64 * k;
                    const float* rp = sb + (size_t)row * NN;
                    const float4 a  = *(const float4*)(rp + 4 * lane);
                    const float4 c2 = *(const float4*)(rp + 256 + 4 * lane);
                    const float vals[8] = {a.x, a.y, a.z, a.w, c2.x, c2.y, c2.z, c2.w};
                    float cur[8];
                    #pragma unroll
                    for (int i = 0; i < 8; ++i)
                        cur[i] = ((colmask >> i) & 1u) ? vals[i] : -1.0f;

                    #pragma unroll
                    for (int j = 0; j < 4; ++j) {
                        float lv = cur[0]; int lslot = 0;
                        #pragma unroll
                        for (int i = 1; i < 8; ++i)
                            if (cur[i] > lv) { lv = cur[i]; lslot = i; }
                        const int lcol = (lslot < 4) ? (4 * lane + lslot)
                                                     : (256 + 4 * lane + lslot - 4);
                        const float mx = bcast63(wave_max_to63(lv));
                        unsigned long long cm2 = __ballot(lv == mx && mx >= 0.0f);
                        int bc2 = 0x7FFFFFFF, bl2 = -1;
                        while (cm2) {
                            const int l2 = __builtin_ctzll(cm2); cm2 &= cm2 - 1;
                            const int cc = __builtin_amdgcn_readlane(lcol, l2);
                            if (cc < bc2) { bc2 = cc; bl2 = l2; }
                        }
                        unsigned long long entry = (mx >= 0.0f)
                            ? pack_entry(mx, bc2)
                            : 0xBF80000000000000ull;   // pack(-1.0f, 0)
                        if (lane == 0) lst[row][j] = entry;
                        if (j == 0 && lane == lr) { rv[k] = mx; rc[k] = bc2; ptr[k] = 0; }
                        if (lane == bl2) {
                            #pragma unroll
                            for (int i = 0; i < 8; ++i)
                                if (i == lslot) cur[i] = -1.0f;
                        }
                    }
                }
            }
        }
    }
}

extern "C" void kernel_launch(void* const* d_in, const int* in_sizes, int n_in,
                              void* d_out, int out_size, void* d_ws, size_t ws_size,
                              hipStream_t stream) {
    const float* s = (const float*)d_in[0];
    float* out = (float*)d_out;

    build_top<<<dim3(BATCH * NN / 4), dim3(256), 0, stream>>>(s, out);
    greedy_match<<<dim3(BATCH), dim3(64), 0, stream>>>(s, out);
}